// Round 1
// 289.923 us; speedup vs baseline: 1.1075x; 1.1075x over previous
//
#include <hip/hip_runtime.h>

#define NTOK 16384
#define BATCH 4

typedef __attribute__((ext_vector_type(8))) short bf16x8;
typedef __attribute__((ext_vector_type(8))) unsigned short ushort8;
typedef __attribute__((ext_vector_type(4))) float f32x4;

__device__ __forceinline__ unsigned short f2bf(float f) {
  union { float f; unsigned int u; } c; c.f = f;
  unsigned int r = c.u + 0x7fff + ((c.u >> 16) & 1);  // RTN-even
  return (unsigned short)(r >> 16);
}

__global__ __launch_bounds__(256) void zero_f(float* __restrict__ p, int n) {
  int i = blockIdx.x * 256 + threadIdx.x;
  if (i < n) p[i] = 0.f;
}

// voxel fp32 -> bf16 (memory-bound pre-pass; removes conversion from GEMM)
__global__ __launch_bounds__(256) void convx(const float* __restrict__ in,
                                             unsigned short* __restrict__ out,
                                             int n8) {
  for (int i = blockIdx.x * 256 + threadIdx.x; i < n8; i += gridDim.x * 256) {
    float4 a = *(const float4*)(in + 8 * (size_t)i);
    float4 b = *(const float4*)(in + 8 * (size_t)i + 4);
    ushort8 o;
    o[0] = f2bf(a.x); o[1] = f2bf(a.y); o[2] = f2bf(a.z); o[3] = f2bf(a.w);
    o[4] = f2bf(b.x); o[5] = f2bf(b.y); o[6] = f2bf(b.z); o[7] = f2bf(b.w);
    *(ushort8*)(out + 8 * (size_t)i) = o;
  }
}

// transpose+convert weights; block 1024 converts cb -> cbbT[l][j] = cb[j][l]
__global__ __launch_bounds__(256) void convw(const float* __restrict__ w_qkv,
                                             const float* __restrict__ w_proj,
                                             const float* __restrict__ cb,
                                             unsigned short* __restrict__ wqT,
                                             unsigned short* __restrict__ wpT,
                                             unsigned short* __restrict__ cbbT) {
  int n = blockIdx.x, k = threadIdx.x;
  if (n < 768) wqT[n * 256 + k] = f2bf(w_qkv[(size_t)k * 768 + n]);
  else if (n < 1024) wpT[(n - 768) * 256 + k] = f2bf(w_proj[(size_t)k * 256 + (n - 768)]);
  else if (k < 64) {
    for (int j = 0; j < 64; ++j) cbbT[k * 64 + j] = f2bf(cb[j * 64 + k]);
  }
}

// C[M,N] = A[M,K=256] @ BT[N,K]^T (+bias). MFMA bf16. Tile 128x128, 4 waves.
// K=256 fixed: ALL global loads issued upfront into registers (single HBM
// latency exposure per block), then 4 LDS-staged K-tiles, double-buffered
// LDS -> one barrier per tile. A is bf16 (pre-converted).
template <int ADD_BIAS, int C_BF16>
__global__ __launch_bounds__(256, 2) void gemm_mfma(const unsigned short* __restrict__ Ab,
                                                    const unsigned short* __restrict__ BT,
                                                    const float* __restrict__ bias,
                                                    void* __restrict__ Cv,
                                                    int N, int K, int lda) {
  __shared__ unsigned short As[2][128][72];
  __shared__ unsigned short Bs[2][128][72];
  const int tid = threadIdx.x;
  // XCD swizzle: dispatch id c mod 8 = XCD (heuristic; correctness-neutral)
  int flat = blockIdx.y * gridDim.x + blockIdx.x;
  int xc = flat & 7, t = flat >> 3;
  int gx = gridDim.x, ypx = gridDim.y >> 3;
  int bx = t % gx, by = xc * ypx + t / gx;
  const int bn = bx * 128, bm = by * 128;
  const int lane = tid & 63;
  const int wv = tid >> 6;
  const int wm = wv & 1, wn = wv >> 1;
  const int m16 = lane & 15, quad = lane >> 4;

  const int srow = tid >> 1;
  const int scol = (tid & 1) * 32;

  // ---- issue ALL loads (K=256 -> 4 tiles x 4 ushort8 each for A and B) ----
  ushort8 ra[4][4], rb[4][4];
  {
    const unsigned short* ga = Ab + (size_t)(bm + srow) * lda + scol;
    const unsigned short* gb = BT + (size_t)(bn + srow) * K + scol;
#pragma unroll
    for (int kt = 0; kt < 4; ++kt)
#pragma unroll
      for (int i = 0; i < 4; ++i) {
        ra[kt][i] = *(const ushort8*)(ga + kt * 64 + 8 * i);
        rb[kt][i] = *(const ushort8*)(gb + kt * 64 + 8 * i);
      }
  }

  f32x4 acc[4][4];
#pragma unroll
  for (int r = 0; r < 4; ++r)
#pragma unroll
    for (int c = 0; c < 4; ++c) acc[r][c] = (f32x4){0.f, 0.f, 0.f, 0.f};

#pragma unroll
  for (int kt = 0; kt < 4; ++kt) {
    const int bufi = kt & 1;
#pragma unroll
    for (int i = 0; i < 4; ++i) {
      *(ushort8*)&As[bufi][srow][scol + 8 * i] = ra[kt][i];
      *(ushort8*)&Bs[bufi][srow][scol + 8 * i] = rb[kt][i];
    }
    __syncthreads();
    // double-buffer: next tile writes the other buffer; the kt+1 barrier
    // orders this tile's reads before the kt+2 overwrite. One barrier/tile.
#pragma unroll
    for (int ks = 0; ks < 64; ks += 32) {
      bf16x8 af[4], bf[4];
#pragma unroll
      for (int r = 0; r < 4; ++r)
        af[r] = *(const bf16x8*)&As[bufi][wm * 64 + r * 16 + m16][ks + quad * 8];
#pragma unroll
      for (int c = 0; c < 4; ++c)
        bf[c] = *(const bf16x8*)&Bs[bufi][wn * 64 + c * 16 + m16][ks + quad * 8];
#pragma unroll
      for (int r = 0; r < 4; ++r)
#pragma unroll
        for (int c = 0; c < 4; ++c)
          acc[r][c] = __builtin_amdgcn_mfma_f32_16x16x32_bf16(af[r], bf[c], acc[r][c], 0, 0, 0);
    }
  }

#pragma unroll
  for (int c = 0; c < 4; ++c) {
    int col = bn + wn * 64 + c * 16 + m16;
    float bv = ADD_BIAS ? bias[col] : 0.f;
#pragma unroll
    for (int r = 0; r < 4; ++r) {
      int row0 = bm + wm * 64 + r * 16 + quad * 4;
#pragma unroll
      for (int i = 0; i < 4; ++i) {
        if (C_BF16)
          ((unsigned short*)Cv)[(size_t)(row0 + i) * N + col] = f2bf(acc[r][c][i] + bv);
        else
          ((float*)Cv)[(size_t)(row0 + i) * N + col] = acc[r][c][i] + bv;
      }
    }
  }
}

// ---- pooling via MFMA: part[b][tch][cl 64][ch 512] over 256-token chunks ----
__global__ __launch_bounds__(256) void pool_mfma(const float* __restrict__ A,
                                                 const unsigned short* __restrict__ qkv,
                                                 float* __restrict__ part) {
  __shared__ unsigned short At[64][40];
  __shared__ unsigned short KVt[128][40];
  const int tid = threadIdx.x;
  const int tch = blockIdx.x, cblk = blockIdx.y, b = blockIdx.z;
  const int w = tid >> 6, lane = tid & 63;
  const int m16 = lane & 15, quad = lane >> 4;
  const size_t row0 = (size_t)b * NTOK + (size_t)tch * 256;
  const int cb0 = cblk * 128;

  f32x4 acc[4][2];
#pragma unroll
  for (int r = 0; r < 4; ++r)
#pragma unroll
    for (int c = 0; c < 2; ++c) acc[r][c] = (f32x4){0.f, 0.f, 0.f, 0.f};

  ushort8 pkv[2];
  float4 pav[2];
  auto loadG = [&](int t0) {
#pragma unroll
    for (int u = 0; u < 2; ++u) {
      int idx = tid + u * 256;
      int tok = idx & 31, g = idx >> 5;
      pkv[u] = *(const ushort8*)(qkv + (row0 + t0 + tok) * 768 + 256 + cb0 + g * 8);
      pav[u] = *(const float4*)(A + (row0 + t0 + tok) * 64 + g * 4);
    }
  };
  loadG(0);

  for (int ks = 0; ks < 8; ++ks) {
    __syncthreads();
#pragma unroll
    for (int u = 0; u < 2; ++u) {
      int idx = tid + u * 256;
      int tok = idx & 31, g = idx >> 5;
#pragma unroll
      for (int i = 0; i < 8; ++i) KVt[g * 8 + i][tok] = (unsigned short)pkv[u][i];
      At[g * 4 + 0][tok] = f2bf(pav[u].x);
      At[g * 4 + 1][tok] = f2bf(pav[u].y);
      At[g * 4 + 2][tok] = f2bf(pav[u].z);
      At[g * 4 + 3][tok] = f2bf(pav[u].w);
    }
    __syncthreads();
    if (ks + 1 < 8) loadG((ks + 1) * 32);
    bf16x8 af[4], bfr[2];
#pragma unroll
    for (int r = 0; r < 4; ++r) af[r] = *(const bf16x8*)&At[r * 16 + m16][quad * 8];
#pragma unroll
    for (int c = 0; c < 2; ++c) bfr[c] = *(const bf16x8*)&KVt[w * 32 + c * 16 + m16][quad * 8];
#pragma unroll
    for (int r = 0; r < 4; ++r)
#pragma unroll
      for (int c = 0; c < 2; ++c)
        acc[r][c] = __builtin_amdgcn_mfma_f32_16x16x32_bf16(af[r], bfr[c], acc[r][c], 0, 0, 0);
  }

  float* pp = part + (((size_t)b * 64 + tch) * 64) * 512 + cb0;
#pragma unroll
  for (int r = 0; r < 4; ++r)
#pragma unroll
    for (int c = 0; c < 2; ++c)
#pragma unroll
      for (int i = 0; i < 4; ++i) {
        int cl = r * 16 + quad * 4 + i;
        int ch = w * 32 + c * 16 + m16;
        pp[(size_t)cl * 512 + ch] = acc[r][c][i];
      }
}

// reduce 64 chunks -> bf16 kcb[b][h][cl][d] (scaled) and vcbT[b][h][d][cl]
__global__ __launch_bounds__(256) void pool2(const float* __restrict__ part,
                                             const float* __restrict__ asum,
                                             unsigned short* __restrict__ kcb,
                                             unsigned short* __restrict__ vcbT) {
  int id = blockIdx.x * 256 + threadIdx.x;  // 0..131071
  int c = id & 511;
  int cl = (id >> 9) & 63;
  int b = id >> 15;
  const float* pp = part + ((size_t)b * 64 * 64 + cl) * 512 + c;
  float s = 0.f;
#pragma unroll 4
  for (int t = 0; t < 64; ++t) s += pp[(size_t)t * 32768];
  float denom = asum[b * 64 + cl] + 1e-8f;
  int p = c >> 8, h = (c >> 5) & 7, d = c & 31;
  if (p == 0)
    kcb[(((size_t)b * 8 + h) * 64 + cl) * 32 + d] = f2bf(s * 0.17677669529663687f / denom);
  else
    vcbT[(((size_t)b * 8 + h) * 32 + d) * 64 + cl] = f2bf(s / denom);
}

__global__ __launch_bounds__(256) void asum_kernel(const float* __restrict__ A,
                                                   float* __restrict__ asum) {
  __shared__ float red[4][64];
  const int ch = blockIdx.x, b = blockIdx.y;
  const int jq = threadIdx.x >> 6, k = threadIdx.x & 63;
  const size_t row0 = (size_t)b * NTOK + (size_t)ch * 256;
  const float* ap = A + (row0 + jq) * 64 + k;
  float s = 0.f;
#pragma unroll 4
  for (int j = 0; j < 64; ++j) s += ap[(size_t)j * 256];
  red[jq][k] = s;
  __syncthreads();
  if (threadIdx.x < 64) {
    float v = red[0][k] + red[1][k] + red[2][k] + red[3][k];
    atomicAdd(&asum[b * 64 + k], v);
  }
}

// ---- fused attention: scores = [q|A]@[kc;cbT]^T (MFMA, bias folded as K-dims),
// LDS softmax, x = P@vcT (MFMA). 128 tokens x 1 head per block. ----
__global__ __launch_bounds__(256) void attn_mfma(const float* __restrict__ A,
                                                 unsigned short* __restrict__ qkv,
                                                 const unsigned short* __restrict__ kcb,
                                                 const unsigned short* __restrict__ vcbT,
                                                 const unsigned short* __restrict__ cbbT) {
  __shared__ __align__(16) char lds[62976];
  unsigned short* QA = (unsigned short*)lds;             // [128][104]
  unsigned short* SB = (unsigned short*)(lds + 26624);   // [64][104]
  float* S = (float*)lds;                                // [128][68] (alias QA+SB)
  unsigned short* P = (unsigned short*)(lds + 39936);    // [128][72]
  unsigned short* VT = (unsigned short*)(lds + 58368);   // [32][72]

  const int tid = threadIdx.x;
  const int nb = blockIdx.x, h = blockIdx.y, b = blockIdx.z;
  const int w = tid >> 6, lane = tid & 63;
  const int m16 = lane & 15, quad = lane >> 4;
  const size_t row0 = (size_t)b * NTOK + (size_t)nb * 128;

  // ---- stage ----
  {
    int r = tid >> 1, half = tid & 1;
    const unsigned short* qp = qkv + (row0 + r) * 768 + h * 32 + half * 16;
    ushort8 q0 = *(const ushort8*)qp;
    ushort8 q1 = *(const ushort8*)(qp + 8);
    *(ushort8*)&QA[r * 104 + half * 16] = q0;
    *(ushort8*)&QA[r * 104 + half * 16 + 8] = q1;

    const float* ap = A + (row0 + r) * 64 + half * 32;
    unsigned short hb[32];
#pragma unroll
    for (int u = 0; u < 8; ++u) {
      float4 v = *(const float4*)(ap + 4 * u);
      hb[4 * u + 0] = f2bf(v.x); hb[4 * u + 1] = f2bf(v.y);
      hb[4 * u + 2] = f2bf(v.z); hb[4 * u + 3] = f2bf(v.w);
    }
#pragma unroll
    for (int u = 0; u < 4; ++u)
      *(ushort8*)&QA[r * 104 + 32 + half * 32 + 8 * u] = *(ushort8*)&hb[8 * u];

    if (tid < 64) {
      const unsigned short* kp = kcb + (((size_t)b * 8 + h) * 64 + tid) * 32;
#pragma unroll
      for (int u = 0; u < 4; ++u)
        *(ushort8*)&SB[tid * 104 + 8 * u] = *(const ushort8*)(kp + 8 * u);
    }
    if (tid < 128) {
      int l = tid >> 1, off = (tid & 1) * 32;
      const unsigned short* cp = cbbT + l * 64 + off;
#pragma unroll
      for (int u = 0; u < 4; ++u)
        *(ushort8*)&SB[l * 104 + 32 + off + 8 * u] = *(const ushort8*)(cp + 8 * u);
    }
    if (tid < 64) {
      int d = tid >> 1, off = (tid & 1) * 32;
      const unsigned short* vp = vcbT + (((size_t)b * 8 + h) * 32 + d) * 64 + off;
#pragma unroll
      for (int u = 0; u < 4; ++u)
        *(ushort8*)&VT[d * 72 + off + 8 * u] = *(const ushort8*)(vp + 8 * u);
    }
  }
  __syncthreads();

  // ---- scores ----
  f32x4 acc[2][4];
#pragma unroll
  for (int r = 0; r < 2; ++r)
#pragma unroll
    for (int c = 0; c < 4; ++c) acc[r][c] = (f32x4){0.f, 0.f, 0.f, 0.f};
#pragma unroll
  for (int kc3 = 0; kc3 < 96; kc3 += 32) {
    bf16x8 af[2], bf[4];
#pragma unroll
    for (int rt = 0; rt < 2; ++rt)
      af[rt] = *(const bf16x8*)&QA[(w * 32 + rt * 16 + m16) * 104 + kc3 + quad * 8];
#pragma unroll
    for (int nt = 0; nt < 4; ++nt)
      bf[nt] = *(const bf16x8*)&SB[(nt * 16 + m16) * 104 + kc3 + quad * 8];
#pragma unroll
    for (int rt = 0; rt < 2; ++rt)
#pragma unroll
      for (int nt = 0; nt < 4; ++nt)
        acc[rt][nt] = __builtin_amdgcn_mfma_f32_16x16x32_bf16(af[rt], bf[nt], acc[rt][nt], 0, 0, 0);
  }
  __syncthreads();  // frag reads done before S overwrites QA/SB

#pragma unroll
  for (int rt = 0; rt < 2; ++rt)
#pragma unroll
    for (int nt = 0; nt < 4; ++nt)
#pragma unroll
      for (int i = 0; i < 4; ++i)
        S[(w * 32 + rt * 16 + quad * 4 + i) * 68 + nt * 16 + m16] = acc[rt][nt][i];
  __syncthreads();

  // ---- softmax (one thread per token row) ----
  if (tid < 128) {
    float sc[64];
#pragma unroll
    for (int u = 0; u < 16; ++u) *(float4*)(sc + 4 * u) = *(const float4*)&S[tid * 68 + 4 * u];
    float m = sc[0];
#pragma unroll
    for (int k = 1; k < 64; ++k) m = fmaxf(m, sc[k]);
    float l = 0.f;
#pragma unroll
    for (int k = 0; k < 64; ++k) {
      float e = __expf(sc[k] - m);
      sc[k] = e;
      l += e;
    }
    float rl = 1.f / l;
    unsigned short hp[64];
#pragma unroll
    for (int k = 0; k < 64; ++k) hp[k] = f2bf(sc[k] * rl);
#pragma unroll
    for (int u = 0; u < 8; ++u) *(ushort8*)&P[tid * 72 + 8 * u] = *(ushort8*)&hp[8 * u];
  }
  __syncthreads();

  // ---- x = P @ vcT ----
  f32x4 acc2[2][2];
#pragma unroll
  for (int r = 0; r < 2; ++r)
#pragma unroll
    for (int c = 0; c < 2; ++c) acc2[r][c] = (f32x4){0.f, 0.f, 0.f, 0.f};
#pragma unroll
  for (int kch = 0; kch < 64; kch += 32) {
    bf16x8 af2[2], bf2[2];
#pragma unroll
    for (int rt = 0; rt < 2; ++rt)
      af2[rt] = *(const bf16x8*)&P[(w * 32 + rt * 16 + m16) * 72 + kch + quad * 8];
#pragma unroll
    for (int nt = 0; nt < 2; ++nt)
      bf2[nt] = *(const bf16x8*)&VT[(nt * 16 + m16) * 72 + kch + quad * 8];
#pragma unroll
    for (int rt = 0; rt < 2; ++rt)
#pragma unroll
      for (int nt = 0; nt < 2; ++nt)
        acc2[rt][nt] = __builtin_amdgcn_mfma_f32_16x16x32_bf16(af2[rt], bf2[nt], acc2[rt][nt], 0, 0, 0);
  }

#pragma unroll
  for (int rt = 0; rt < 2; ++rt)
#pragma unroll
    for (int nt = 0; nt < 2; ++nt)
#pragma unroll
      for (int i = 0; i < 4; ++i) {
        int tr = w * 32 + rt * 16 + quad * 4 + i;
        int d = nt * 16 + m16;
        qkv[(row0 + tr) * 768 + h * 32 + d] = f2bf(acc2[rt][nt][i]);
      }
}

extern "C" void kernel_launch(void* const* d_in, const int* in_sizes, int n_in,
                              void* d_out, int out_size, void* d_ws, size_t ws_size,
                              hipStream_t stream) {
  const float* voxel  = (const float*)d_in[0];
  const float* A      = (const float*)d_in[1];
  const float* w_qkv  = (const float*)d_in[2];
  const float* w_proj = (const float*)d_in[3];
  const float* b_proj = (const float*)d_in[4];
  const float* cb     = (const float*)d_in[5];
  float* out = (float*)d_out;
  (void)in_sizes; (void)n_in; (void)out_size; (void)ws_size;

  // bytes: qkv bf16 100663296 | part 33554432 | asum 1024 | wqT 393216 |
  //        wpT 131072 | kcb 131072 | vcbT 131072 | cbbT 8192   ~= 135 MB
  char* wsb = (char*)d_ws;
  unsigned short* qkv = (unsigned short*)wsb;
  float* part = (float*)(wsb + 100663296);
  float* asum = (float*)(wsb + 100663296 + 33554432);
  unsigned short* wqT  = (unsigned short*)(wsb + 134218752);
  unsigned short* wpT  = wqT + 196608;
  unsigned short* kcb  = wpT + 65536;
  unsigned short* vcbT = kcb + 65536;
  unsigned short* cbbT = vcbT + 65536;
  // xb (bf16 voxel, 33554432 B) aliases part: dead before pool_mfma writes part
  unsigned short* xb = (unsigned short*)part;

  zero_f<<<1, 256, 0, stream>>>(asum, 256);
  convw<<<1025, 256, 0, stream>>>(w_qkv, w_proj, cb, wqT, wpT, cbbT);
  convx<<<2048, 256, 0, stream>>>(voxel, xb, 2097152);

  // qkv(bf16) = xb @ w_qkv
  gemm_mfma<0, 1><<<dim3(6, 512), 256, 0, stream>>>(xb, wqT, nullptr, qkv,
                                                    768, 256, 256);

  asum_kernel<<<dim3(64, BATCH), 256, 0, stream>>>(A, asum);
  pool_mfma<<<dim3(64, 4, BATCH), 256, 0, stream>>>(A, qkv, part);
  pool2<<<512, 256, 0, stream>>>(part, asum, kcb, vcbT);

  // fused attention (bias folded in); x bf16 -> q slot of qkv
  attn_mfma<<<dim3(NTOK / 128, 8, BATCH), 256, 0, stream>>>(A, qkv, kcb, vcbT, cbbT);

  // out = x @ w_proj + b_proj : x bf16 in q slot of qkv (lda 768 shorts)
  gemm_mfma<1, 0><<<dim3(2, 512), 256, 0, stream>>>(qkv, wpT, b_proj, out,
                                                    256, 256, 768);
}

// Round 2
// 270.108 us; speedup vs baseline: 1.1887x; 1.0734x over previous
//
#include <hip/hip_runtime.h>

#define NTOK 16384
#define BATCH 4

typedef __attribute__((ext_vector_type(8))) short bf16x8;
typedef __attribute__((ext_vector_type(8))) unsigned short ushort8;
typedef __attribute__((ext_vector_type(4))) float f32x4;

__device__ __forceinline__ unsigned short f2bf(float f) {
  union { float f; unsigned int u; } c; c.f = f;
  unsigned int r = c.u + 0x7fff + ((c.u >> 16) & 1);  // RTN-even
  return (unsigned short)(r >> 16);
}

__global__ __launch_bounds__(256) void zero_f(float* __restrict__ p, int n) {
  int i = blockIdx.x * 256 + threadIdx.x;
  if (i < n) p[i] = 0.f;
}

// fp32 -> bf16 pre-pass: voxel (2097152 grp) then A (524288 grp)
__global__ __launch_bounds__(256) void convx2(const float* __restrict__ voxel,
                                              const float* __restrict__ A,
                                              unsigned short* __restrict__ xb,
                                              unsigned short* __restrict__ Ab) {
  for (int i = blockIdx.x * 256 + threadIdx.x; i < 2621440; i += gridDim.x * 256) {
    const float* src; unsigned short* dst; int j;
    if (i < 2097152) { j = i; src = voxel; dst = xb; }
    else { j = i - 2097152; src = A; dst = Ab; }
    float4 a = *(const float4*)(src + 8 * (size_t)j);
    float4 b = *(const float4*)(src + 8 * (size_t)j + 4);
    ushort8 o;
    o[0] = f2bf(a.x); o[1] = f2bf(a.y); o[2] = f2bf(a.z); o[3] = f2bf(a.w);
    o[4] = f2bf(b.x); o[5] = f2bf(b.y); o[6] = f2bf(b.z); o[7] = f2bf(b.w);
    *(ushort8*)(dst + 8 * (size_t)j) = o;
  }
}

// transpose+convert weights; block 1024 converts cb -> cbbT[l][j] = cb[j][l]
__global__ __launch_bounds__(256) void convw(const float* __restrict__ w_qkv,
                                             const float* __restrict__ w_proj,
                                             const float* __restrict__ cb,
                                             unsigned short* __restrict__ wqT,
                                             unsigned short* __restrict__ wpT,
                                             unsigned short* __restrict__ cbbT) {
  int n = blockIdx.x, k = threadIdx.x;
  if (n < 768) wqT[n * 256 + k] = f2bf(w_qkv[(size_t)k * 768 + n]);
  else if (n < 1024) wpT[(n - 768) * 256 + k] = f2bf(w_proj[(size_t)k * 256 + (n - 768)]);
  else if (k < 64) {
    for (int j = 0; j < 64; ++j) cbbT[k * 64 + j] = f2bf(cb[j * 64 + k]);
  }
}

// C[M,N] = A[M,K=256] @ BT[N,K]^T (+bias). MFMA bf16. Tile 128x128, 4 waves.
// All global loads issued upfront; double-buffered LDS, one barrier per tile.
template <int ADD_BIAS, int C_BF16>
__global__ __launch_bounds__(256, 2) void gemm_mfma(const unsigned short* __restrict__ Ab,
                                                    const unsigned short* __restrict__ BT,
                                                    const float* __restrict__ bias,
                                                    void* __restrict__ Cv,
                                                    int N, int K, int lda) {
  __shared__ unsigned short As[2][128][72];
  __shared__ unsigned short Bs[2][128][72];
  const int tid = threadIdx.x;
  int flat = blockIdx.y * gridDim.x + blockIdx.x;
  int xc = flat & 7, t = flat >> 3;
  int gx = gridDim.x, ypx = gridDim.y >> 3;
  int bx = t % gx, by = xc * ypx + t / gx;
  const int bn = bx * 128, bm = by * 128;
  const int lane = tid & 63;
  const int wv = tid >> 6;
  const int wm = wv & 1, wn = wv >> 1;
  const int m16 = lane & 15, quad = lane >> 4;

  const int srow = tid >> 1;
  const int scol = (tid & 1) * 32;

  ushort8 ra[4][4], rb[4][4];
  {
    const unsigned short* ga = Ab + (size_t)(bm + srow) * lda + scol;
    const unsigned short* gb = BT + (size_t)(bn + srow) * K + scol;
#pragma unroll
    for (int kt = 0; kt < 4; ++kt)
#pragma unroll
      for (int i = 0; i < 4; ++i) {
        ra[kt][i] = *(const ushort8*)(ga + kt * 64 + 8 * i);
        rb[kt][i] = *(const ushort8*)(gb + kt * 64 + 8 * i);
      }
  }

  f32x4 acc[4][4];
#pragma unroll
  for (int r = 0; r < 4; ++r)
#pragma unroll
    for (int c = 0; c < 4; ++c) acc[r][c] = (f32x4){0.f, 0.f, 0.f, 0.f};

#pragma unroll
  for (int kt = 0; kt < 4; ++kt) {
    const int bufi = kt & 1;
#pragma unroll
    for (int i = 0; i < 4; ++i) {
      *(ushort8*)&As[bufi][srow][scol + 8 * i] = ra[kt][i];
      *(ushort8*)&Bs[bufi][srow][scol + 8 * i] = rb[kt][i];
    }
    __syncthreads();
#pragma unroll
    for (int ks = 0; ks < 64; ks += 32) {
      bf16x8 af[4], bf[4];
#pragma unroll
      for (int r = 0; r < 4; ++r)
        af[r] = *(const bf16x8*)&As[bufi][wm * 64 + r * 16 + m16][ks + quad * 8];
#pragma unroll
      for (int c = 0; c < 4; ++c)
        bf[c] = *(const bf16x8*)&Bs[bufi][wn * 64 + c * 16 + m16][ks + quad * 8];
#pragma unroll
      for (int r = 0; r < 4; ++r)
#pragma unroll
        for (int c = 0; c < 4; ++c)
          acc[r][c] = __builtin_amdgcn_mfma_f32_16x16x32_bf16(af[r], bf[c], acc[r][c], 0, 0, 0);
    }
  }

#pragma unroll
  for (int c = 0; c < 4; ++c) {
    int col = bn + wn * 64 + c * 16 + m16;
    float bv = ADD_BIAS ? bias[col] : 0.f;
#pragma unroll
    for (int r = 0; r < 4; ++r) {
      int row0 = bm + wm * 64 + r * 16 + quad * 4;
#pragma unroll
      for (int i = 0; i < 4; ++i) {
        if (C_BF16)
          ((unsigned short*)Cv)[(size_t)(row0 + i) * N + col] = f2bf(acc[r][c][i] + bv);
        else
          ((float*)Cv)[(size_t)(row0 + i) * N + col] = acc[r][c][i] + bv;
      }
    }
  }
}

// ---- pooling via MFMA: part[b][tch][cl 64][ch 512] over 256-token chunks ----
__global__ __launch_bounds__(256) void pool_mfma(const float* __restrict__ A,
                                                 const unsigned short* __restrict__ qkv,
                                                 float* __restrict__ part) {
  __shared__ unsigned short At[64][40];
  __shared__ unsigned short KVt[128][40];
  const int tid = threadIdx.x;
  const int tch = blockIdx.x, cblk = blockIdx.y, b = blockIdx.z;
  const int w = tid >> 6, lane = tid & 63;
  const int m16 = lane & 15, quad = lane >> 4;
  const size_t row0 = (size_t)b * NTOK + (size_t)tch * 256;
  const int cb0 = cblk * 128;

  f32x4 acc[4][2];
#pragma unroll
  for (int r = 0; r < 4; ++r)
#pragma unroll
    for (int c = 0; c < 2; ++c) acc[r][c] = (f32x4){0.f, 0.f, 0.f, 0.f};

  ushort8 pkv[2];
  float4 pav[2];
  auto loadG = [&](int t0) {
#pragma unroll
    for (int u = 0; u < 2; ++u) {
      int idx = tid + u * 256;
      int tok = idx & 31, g = idx >> 5;
      pkv[u] = *(const ushort8*)(qkv + (row0 + t0 + tok) * 768 + 256 + cb0 + g * 8);
      pav[u] = *(const float4*)(A + (row0 + t0 + tok) * 64 + g * 4);
    }
  };
  loadG(0);

  for (int ks = 0; ks < 8; ++ks) {
    __syncthreads();
#pragma unroll
    for (int u = 0; u < 2; ++u) {
      int idx = tid + u * 256;
      int tok = idx & 31, g = idx >> 5;
#pragma unroll
      for (int i = 0; i < 8; ++i) KVt[g * 8 + i][tok] = (unsigned short)pkv[u][i];
      At[g * 4 + 0][tok] = f2bf(pav[u].x);
      At[g * 4 + 1][tok] = f2bf(pav[u].y);
      At[g * 4 + 2][tok] = f2bf(pav[u].z);
      At[g * 4 + 3][tok] = f2bf(pav[u].w);
    }
    __syncthreads();
    if (ks + 1 < 8) loadG((ks + 1) * 32);
    bf16x8 af[4], bfr[2];
#pragma unroll
    for (int r = 0; r < 4; ++r) af[r] = *(const bf16x8*)&At[r * 16 + m16][quad * 8];
#pragma unroll
    for (int c = 0; c < 2; ++c) bfr[c] = *(const bf16x8*)&KVt[w * 32 + c * 16 + m16][quad * 8];
#pragma unroll
    for (int r = 0; r < 4; ++r)
#pragma unroll
      for (int c = 0; c < 2; ++c)
        acc[r][c] = __builtin_amdgcn_mfma_f32_16x16x32_bf16(af[r], bfr[c], acc[r][c], 0, 0, 0);
  }

  float* pp = part + (((size_t)b * 64 + tch) * 64) * 512 + cb0;
#pragma unroll
  for (int r = 0; r < 4; ++r)
#pragma unroll
    for (int c = 0; c < 2; ++c)
#pragma unroll
      for (int i = 0; i < 4; ++i) {
        int cl = r * 16 + quad * 4 + i;
        int ch = w * 32 + c * 16 + m16;
        pp[(size_t)cl * 512 + ch] = acc[r][c][i];
      }
}

// reduce 64 chunks -> bf16 kcb[b][h][cl][d] (scaled) and vcbT[b][h][d][cl]
__global__ __launch_bounds__(256) void pool2(const float* __restrict__ part,
                                             const float* __restrict__ asum,
                                             unsigned short* __restrict__ kcb,
                                             unsigned short* __restrict__ vcbT) {
  int id = blockIdx.x * 256 + threadIdx.x;  // 0..131071
  int c = id & 511;
  int cl = (id >> 9) & 63;
  int b = id >> 15;
  const float* pp = part + ((size_t)b * 64 * 64 + cl) * 512 + c;
  float s = 0.f;
#pragma unroll 4
  for (int t = 0; t < 64; ++t) s += pp[(size_t)t * 32768];
  float denom = asum[b * 64 + cl] + 1e-8f;
  int p = c >> 8, h = (c >> 5) & 7, d = c & 31;
  if (p == 0)
    kcb[(((size_t)b * 8 + h) * 64 + cl) * 32 + d] = f2bf(s * 0.17677669529663687f / denom);
  else
    vcbT[(((size_t)b * 8 + h) * 32 + d) * 64 + cl] = f2bf(s / denom);
}

__global__ __launch_bounds__(256) void asum_kernel(const float* __restrict__ A,
                                                   float* __restrict__ asum) {
  __shared__ float red[4][64];
  const int ch = blockIdx.x, b = blockIdx.y;
  const int jq = threadIdx.x >> 6, k = threadIdx.x & 63;
  const size_t row0 = (size_t)b * NTOK + (size_t)ch * 256;
  const float* ap = A + (row0 + jq) * 64 + k;
  float s = 0.f;
#pragma unroll 4
  for (int j = 0; j < 64; ++j) s += ap[(size_t)j * 256];
  red[jq][k] = s;
  __syncthreads();
  if (threadIdx.x < 64) {
    float v = red[0][k] + red[1][k] + red[2][k] + red[3][k];
    atomicAdd(&asum[b * 64 + k], v);
  }
}

// ---- fused attention v2: 128 tokens x 4 heads per block.
// bias = A@cbT computed ONCE via MFMA, held in f32 accumulator regs (bacc);
// per head: scores = bacc + q@kc^T (single K=32 step), in-register softmax
// (16-lane shuffle reduce), P -> LDS (same-wave rows), PV MFMA.
// LDS 38400 B -> 4 blocks/CU. Next head's Q/KC/VT prefetched into regs. ----
__global__ __launch_bounds__(256) void attn_mfma(const unsigned short* __restrict__ Ab,
                                                 unsigned short* __restrict__ qkv,
                                                 const unsigned short* __restrict__ kcb,
                                                 const unsigned short* __restrict__ vcbT,
                                                 const unsigned short* __restrict__ cbbT) {
  __shared__ __align__(16) char lds[38400];
  unsigned short* PA  = (unsigned short*)lds;            // [128][72]: A tile, then P
  unsigned short* Qs  = (unsigned short*)(lds + 18432);  // [128][40]
  unsigned short* KCs = (unsigned short*)(lds + 28672);  // [64][40]
  unsigned short* VTs = (unsigned short*)(lds + 33792);  // [32][72]
  unsigned short* CBs = (unsigned short*)(lds + 28672);  // [64][72] alias KC+VT

  const int tid = threadIdx.x;
  const int nb = blockIdx.x, hq = blockIdx.y, b = blockIdx.z;
  const int h0 = hq * 4;
  const int w = tid >> 6, lane = tid & 63;
  const int m16 = lane & 15, quad = lane >> 4;
  const size_t row0 = (size_t)b * NTOK + (size_t)nb * 128;

  const int r2 = tid >> 1, half = tid & 1;  // A/Q staging: row, 32-short half
  const int l4 = tid >> 2, s3 = tid & 3;    // KC/cb staging
  const int d8 = tid >> 3, s7 = tid & 7;    // VT staging

  // ---- prologue loads: A tile + cbbT + head0 Q/KC/VT ----
  ushort8 rA[4], rcb[2];
  {
    const unsigned short* ap = Ab + (row0 + r2) * 64 + half * 32;
#pragma unroll
    for (int u = 0; u < 4; ++u) rA[u] = *(const ushort8*)(ap + 8 * u);
    const unsigned short* cp = cbbT + l4 * 64 + s3 * 16;
    rcb[0] = *(const ushort8*)cp;
    rcb[1] = *(const ushort8*)(cp + 8);
  }
  ushort8 rq[2][2], rkc[2], rvt[2];
  {
    const unsigned short* qp = qkv + (row0 + r2) * 768 + h0 * 32 + half * 16;
    rq[0][0] = *(const ushort8*)qp;
    rq[0][1] = *(const ushort8*)(qp + 8);
    rkc[0] = *(const ushort8*)(kcb + (((size_t)b * 8 + h0) * 64 + l4) * 32 + s3 * 8);
    rvt[0] = *(const ushort8*)(vcbT + (((size_t)b * 8 + h0) * 32 + d8) * 64 + s7 * 8);
  }
#pragma unroll
  for (int u = 0; u < 4; ++u) *(ushort8*)&PA[r2 * 72 + half * 32 + 8 * u] = rA[u];
  *(ushort8*)&CBs[l4 * 72 + s3 * 16] = rcb[0];
  *(ushort8*)&CBs[l4 * 72 + s3 * 16 + 8] = rcb[1];
  __syncthreads();

  // ---- bias (128x64, K=64) into registers ----
  f32x4 bacc[2][4];
#pragma unroll
  for (int rt = 0; rt < 2; ++rt)
#pragma unroll
    for (int nt = 0; nt < 4; ++nt) bacc[rt][nt] = (f32x4){0.f, 0.f, 0.f, 0.f};
#pragma unroll
  for (int ks = 0; ks < 64; ks += 32) {
    bf16x8 af[2], bf[4];
#pragma unroll
    for (int rt = 0; rt < 2; ++rt)
      af[rt] = *(const bf16x8*)&PA[(w * 32 + rt * 16 + m16) * 72 + ks + quad * 8];
#pragma unroll
    for (int nt = 0; nt < 4; ++nt)
      bf[nt] = *(const bf16x8*)&CBs[(nt * 16 + m16) * 72 + ks + quad * 8];
#pragma unroll
    for (int rt = 0; rt < 2; ++rt)
#pragma unroll
      for (int nt = 0; nt < 4; ++nt)
        bacc[rt][nt] = __builtin_amdgcn_mfma_f32_16x16x32_bf16(af[rt], bf[nt], bacc[rt][nt], 0, 0, 0);
  }
  __syncthreads();  // bias frag reads done; PA/CBs regions reusable

#pragma unroll
  for (int hh = 0; hh < 4; ++hh) {
    const int h = h0 + hh;
    const int cur = hh & 1;
    // stage head hh from regs
    *(ushort8*)&Qs[r2 * 40 + half * 16] = rq[cur][0];
    *(ushort8*)&Qs[r2 * 40 + half * 16 + 8] = rq[cur][1];
    *(ushort8*)&KCs[l4 * 40 + s3 * 8] = rkc[cur];
    *(ushort8*)&VTs[d8 * 72 + s7 * 8] = rvt[cur];
    if (hh < 3) {  // prefetch head hh+1
      const int h1 = h + 1;
      const unsigned short* qp = qkv + (row0 + r2) * 768 + h1 * 32 + half * 16;
      rq[cur ^ 1][0] = *(const ushort8*)qp;
      rq[cur ^ 1][1] = *(const ushort8*)(qp + 8);
      rkc[cur ^ 1] = *(const ushort8*)(kcb + (((size_t)b * 8 + h1) * 64 + l4) * 32 + s3 * 8);
      rvt[cur ^ 1] = *(const ushort8*)(vcbT + (((size_t)b * 8 + h1) * 32 + d8) * 64 + s7 * 8);
    }
    __syncthreads();

    // ---- scores = bias + q @ kc^T (K=32, one step) ----
    f32x4 acc[2][4];
#pragma unroll
    for (int rt = 0; rt < 2; ++rt)
#pragma unroll
      for (int nt = 0; nt < 4; ++nt) acc[rt][nt] = bacc[rt][nt];
    {
      bf16x8 af[2], bf[4];
#pragma unroll
      for (int rt = 0; rt < 2; ++rt)
        af[rt] = *(const bf16x8*)&Qs[(w * 32 + rt * 16 + m16) * 40 + quad * 8];
#pragma unroll
      for (int nt = 0; nt < 4; ++nt)
        bf[nt] = *(const bf16x8*)&KCs[(nt * 16 + m16) * 40 + quad * 8];
#pragma unroll
      for (int rt = 0; rt < 2; ++rt)
#pragma unroll
        for (int nt = 0; nt < 4; ++nt)
          acc[rt][nt] = __builtin_amdgcn_mfma_f32_16x16x32_bf16(af[rt], bf[nt], acc[rt][nt], 0, 0, 0);
    }

    // ---- in-register softmax: row = (quad,i), 64 cols across nt x 16 lanes ----
#pragma unroll
    for (int rt = 0; rt < 2; ++rt) {
      f32x4 mxv, sv;
#pragma unroll
      for (int i = 0; i < 4; ++i)
        mxv[i] = fmaxf(fmaxf(acc[rt][0][i], acc[rt][1][i]),
                       fmaxf(acc[rt][2][i], acc[rt][3][i]));
#pragma unroll
      for (int msk = 1; msk < 16; msk <<= 1)
#pragma unroll
        for (int i = 0; i < 4; ++i) mxv[i] = fmaxf(mxv[i], __shfl_xor(mxv[i], msk));
#pragma unroll
      for (int i = 0; i < 4; ++i) sv[i] = 0.f;
#pragma unroll
      for (int nt = 0; nt < 4; ++nt)
#pragma unroll
        for (int i = 0; i < 4; ++i) {
          float e = __expf(acc[rt][nt][i] - mxv[i]);
          acc[rt][nt][i] = e;
          sv[i] += e;
        }
#pragma unroll
      for (int msk = 1; msk < 16; msk <<= 1)
#pragma unroll
        for (int i = 0; i < 4; ++i) sv[i] += __shfl_xor(sv[i], msk);
#pragma unroll
      for (int i = 0; i < 4; ++i) sv[i] = 1.f / sv[i];
#pragma unroll
      for (int nt = 0; nt < 4; ++nt)
#pragma unroll
        for (int i = 0; i < 4; ++i)
          PA[(w * 32 + rt * 16 + quad * 4 + i) * 72 + nt * 16 + m16] =
              f2bf(acc[rt][nt][i] * sv[i]);
    }
    // P rows written/read by the SAME wave only -> no barrier needed here

    // ---- x = P @ vcT ----
    f32x4 acc2[2][2];
#pragma unroll
    for (int rt = 0; rt < 2; ++rt)
#pragma unroll
      for (int nt = 0; nt < 2; ++nt) acc2[rt][nt] = (f32x4){0.f, 0.f, 0.f, 0.f};
#pragma unroll
    for (int kch = 0; kch < 64; kch += 32) {
      bf16x8 af2[2], bf2[2];
#pragma unroll
      for (int rt = 0; rt < 2; ++rt)
        af2[rt] = *(const bf16x8*)&PA[(w * 32 + rt * 16 + m16) * 72 + kch + quad * 8];
#pragma unroll
      for (int nt = 0; nt < 2; ++nt)
        bf2[nt] = *(const bf16x8*)&VTs[(nt * 16 + m16) * 72 + kch + quad * 8];
#pragma unroll
      for (int rt = 0; rt < 2; ++rt)
#pragma unroll
        for (int nt = 0; nt < 2; ++nt)
          acc2[rt][nt] = __builtin_amdgcn_mfma_f32_16x16x32_bf16(af2[rt], bf2[nt], acc2[rt][nt], 0, 0, 0);
    }

#pragma unroll
    for (int rt = 0; rt < 2; ++rt)
#pragma unroll
      for (int nt = 0; nt < 2; ++nt)
#pragma unroll
        for (int i = 0; i < 4; ++i) {
          int tr = w * 32 + rt * 16 + quad * 4 + i;
          int d = nt * 16 + m16;
          qkv[(row0 + tr) * 768 + h * 32 + d] = f2bf(acc2[rt][nt][i]);
        }
    __syncthreads();  // Q/KC/VT frag reads done before next head's stage
  }
}

extern "C" void kernel_launch(void* const* d_in, const int* in_sizes, int n_in,
                              void* d_out, int out_size, void* d_ws, size_t ws_size,
                              hipStream_t stream) {
  const float* voxel  = (const float*)d_in[0];
  const float* A      = (const float*)d_in[1];
  const float* w_qkv  = (const float*)d_in[2];
  const float* w_proj = (const float*)d_in[3];
  const float* b_proj = (const float*)d_in[4];
  const float* cb     = (const float*)d_in[5];
  float* out = (float*)d_out;
  (void)in_sizes; (void)n_in; (void)out_size; (void)ws_size;

  // ws: qkv bf16 100663296 | part 33554432 | asum 1024 | wqT | wpT | kcb | vcbT | cbbT
  char* wsb = (char*)d_ws;
  unsigned short* qkv = (unsigned short*)wsb;
  float* part = (float*)(wsb + 100663296);
  float* asum = (float*)(wsb + 100663296 + 33554432);
  unsigned short* wqT  = (unsigned short*)(wsb + 134218752);
  unsigned short* wpT  = wqT + 196608;
  unsigned short* kcb  = wpT + 65536;
  unsigned short* vcbT = kcb + 65536;
  unsigned short* cbbT = vcbT + 65536;
  // xb (bf16 voxel) aliases part (dead before pool_mfma writes part)
  unsigned short* xb = (unsigned short*)part;
  // Ab (bf16 A, 8 MB) parked in d_out: dead before the final GEMM writes out
  unsigned short* Ab = (unsigned short*)d_out;

  zero_f<<<1, 256, 0, stream>>>(asum, 256);
  convw<<<1025, 256, 0, stream>>>(w_qkv, w_proj, cb, wqT, wpT, cbbT);
  convx2<<<2048, 256, 0, stream>>>(voxel, A, xb, Ab);

  // qkv(bf16) = xb @ w_qkv
  gemm_mfma<0, 1><<<dim3(6, 512), 256, 0, stream>>>(xb, wqT, nullptr, qkv,
                                                    768, 256, 256);

  asum_kernel<<<dim3(64, BATCH), 256, 0, stream>>>(A, asum);
  pool_mfma<<<dim3(64, 4, BATCH), 256, 0, stream>>>(A, qkv, part);
  pool2<<<512, 256, 0, stream>>>(part, asum, kcb, vcbT);

  // fused attention: 128 tokens x 4 heads per block
  attn_mfma<<<dim3(NTOK / 128, 2, BATCH), 256, 0, stream>>>(Ab, qkv, kcb, vcbT, cbbT);

  // out = x @ w_proj + b_proj : x bf16 in q slot of qkv (lda 768 shorts)
  gemm_mfma<1, 0><<<dim3(2, 512), 256, 0, stream>>>(qkv, wpT, b_proj, out,
                                                    256, 256, 768);
}